// Round 2
// baseline (1008.237 us; speedup 1.0000x reference)
//
#include <hip/hip_runtime.h>

constexpr int EMBED = 64;
constexpr int RBF   = 16;
constexpr int EPB   = 64;   // edges per block
constexpr int EPW   = 16;   // edges per wave (4 waves/block)

// ---------------------------------------------------------------------------
// Edge kernel: per edge, angle + edge MLP (17->64 SiLU 64->64), atomic scatter
// into agg[row]. One wave processes EPW edges; lane = output channel.
// ---------------------------------------------------------------------------
__global__ __launch_bounds__(256) void edge_kernel(
    const float* __restrict__ coord,
    const float* __restrict__ rbf,
    const int* __restrict__ edge_index,   // int32 per harness contract
    const float* __restrict__ W1,
    const float* __restrict__ b1,
    const float* __restrict__ W2,
    const float* __restrict__ b2,
    float* __restrict__ agg,
    long long E)
{
    __shared__ __align__(16) float lds_rbf[EPB * RBF];
    __shared__ int lds_row[EPB];
    __shared__ int lds_col[EPB];
    __shared__ __align__(16) float lds_s[4][EMBED];

    const int tid  = threadIdx.x;
    const int lane = tid & 63;
    const int wave = tid >> 6;
    const long long e0 = (long long)blockIdx.x * EPB;

    // stage this block's 64 edges of rbf (1024 floats) coalesced
    if (e0 + EPB <= E) {
        const float4* src = reinterpret_cast<const float4*>(rbf + e0 * RBF);
        float4* dst = reinterpret_cast<float4*>(lds_rbf);
        dst[tid] = src[tid];
    } else {
        for (int i = tid; i < EPB * RBF; i += 256) {
            long long gi = e0 * RBF + i;
            lds_rbf[i] = (gi < E * (long long)RBF) ? rbf[gi] : 0.0f;
        }
    }
    if (tid < EPB) {
        long long e = e0 + tid;
        lds_row[tid] = (e < E) ? edge_index[e] : 0;
    } else if (tid < 2 * EPB) {
        long long e = e0 + (tid - EPB);
        lds_col[tid - EPB] = (e < E) ? edge_index[E + e] : 0;
    }
    __syncthreads();

    // per-lane weight columns (stay in VGPRs)
    float w1c[RBF + 1];
#pragma unroll
    for (int k = 0; k <= RBF; ++k) w1c[k] = W1[k * EMBED + lane];
    float w2c[EMBED];
#pragma unroll
    for (int j = 0; j < EMBED; ++j) w2c[j] = W2[j * EMBED + lane];
    const float b1v = b1[lane];
    const float b2v = b2[lane];

    const float4* s4 = reinterpret_cast<const float4*>(lds_s[wave]);

#pragma unroll 1
    for (int i = 0; i < EPW; ++i) {
        const int el = wave * EPW + i;
        const long long e = e0 + el;
        if (e >= E) break;
        const int row = lds_row[el];
        const int col = lds_col[el];

        // angle(v, -v) exactly as reference
        const float vx = coord[row * 3 + 0] - coord[col * 3 + 0];
        const float vy = coord[row * 3 + 1] - coord[col * 3 + 1];
        const float vz = coord[row * 3 + 2] - coord[col * 3 + 2];
        float sq = vx * vx + vy * vy;
        sq += vz * vz;
        const float nrm = fmaxf(sqrtf(sq), 1e-12f);
        const float inv = 1.0f / nrm;
        const float vnx = vx * inv, vny = vy * inv, vnz = vz * inv;
        float c = -(vnx * vnx + vny * vny + vnz * vnz);
        c = fminf(fmaxf(c, -1.0f + 1e-8f), 1.0f - 1e-8f);
        const float angle = acosf(c);

        // h1 = [rbf, angle] @ W1 + b1   (lane = out channel)
        float acc = fmaf(angle, w1c[RBF], b1v);
#pragma unroll
        for (int k = 0; k < RBF; ++k)
            acc = fmaf(lds_rbf[el * RBF + k], w1c[k], acc);

        // SiLU
        const float s = acc / (1.0f + __expf(-acc));

        // broadcast s across the wave via wave-synchronous LDS
        lds_s[wave][lane] = s;
        __builtin_amdgcn_wave_barrier();

        // msg = silu(h1) @ W2 + b2
        float acc2 = b2v;
#pragma unroll
        for (int j4 = 0; j4 < EMBED / 4; ++j4) {
            const float4 sv = s4[j4];
            acc2 = fmaf(sv.x, w2c[4 * j4 + 0], acc2);
            acc2 = fmaf(sv.y, w2c[4 * j4 + 1], acc2);
            acc2 = fmaf(sv.z, w2c[4 * j4 + 2], acc2);
            acc2 = fmaf(sv.w, w2c[4 * j4 + 3], acc2);
        }
        __builtin_amdgcn_wave_barrier();

        // coalesced 64-lane atomic scatter-add (one VMEM instr per edge)
        atomicAdd(&agg[(long long)row * EMBED + lane], acc2);
    }
}

// ---------------------------------------------------------------------------
// Node kernel: out = x + W4 @ silu(W3 @ agg + b3) + b4 ; one wave per node
// ---------------------------------------------------------------------------
__global__ __launch_bounds__(256) void node_kernel(
    const float* __restrict__ x,
    const float* __restrict__ agg,
    const float* __restrict__ W3,
    const float* __restrict__ b3,
    const float* __restrict__ W4,
    const float* __restrict__ b4,
    float* __restrict__ out,
    int nn)
{
    __shared__ __align__(16) float lds_s[4][EMBED];
    const int lane = threadIdx.x & 63;
    const int wave = threadIdx.x >> 6;

    float w3c[EMBED], w4c[EMBED];
#pragma unroll
    for (int j = 0; j < EMBED; ++j) w3c[j] = W3[j * EMBED + lane];
#pragma unroll
    for (int j = 0; j < EMBED; ++j) w4c[j] = W4[j * EMBED + lane];
    const float b3v = b3[lane];
    const float b4v = b4[lane];

    const float4* s4 = reinterpret_cast<const float4*>(lds_s[wave]);

    const int wid = blockIdx.x * 4 + wave;
    const int nw  = gridDim.x * 4;
    for (int n = wid; n < nn; n += nw) {
        const long long base = (long long)n * EMBED + lane;
        const float a = agg[base];

        lds_s[wave][lane] = a;
        __builtin_amdgcn_wave_barrier();

        float acc = b3v;
#pragma unroll
        for (int j4 = 0; j4 < EMBED / 4; ++j4) {
            const float4 sv = s4[j4];
            acc = fmaf(sv.x, w3c[4 * j4 + 0], acc);
            acc = fmaf(sv.y, w3c[4 * j4 + 1], acc);
            acc = fmaf(sv.z, w3c[4 * j4 + 2], acc);
            acc = fmaf(sv.w, w3c[4 * j4 + 3], acc);
        }
        const float s = acc / (1.0f + __expf(-acc));

        __builtin_amdgcn_wave_barrier();
        lds_s[wave][lane] = s;
        __builtin_amdgcn_wave_barrier();

        float acc2 = b4v;
#pragma unroll
        for (int j4 = 0; j4 < EMBED / 4; ++j4) {
            const float4 sv = s4[j4];
            acc2 = fmaf(sv.x, w4c[4 * j4 + 0], acc2);
            acc2 = fmaf(sv.y, w4c[4 * j4 + 1], acc2);
            acc2 = fmaf(sv.z, w4c[4 * j4 + 2], acc2);
            acc2 = fmaf(sv.w, w4c[4 * j4 + 3], acc2);
        }
        __builtin_amdgcn_wave_barrier();

        out[base] = x[base] + acc2;
    }
}

extern "C" void kernel_launch(void* const* d_in, const int* in_sizes, int n_in,
                              void* d_out, int out_size, void* d_ws, size_t ws_size,
                              hipStream_t stream) {
    const float* x      = (const float*)d_in[0];
    const float* coord  = (const float*)d_in[1];
    const float* rbf    = (const float*)d_in[2];
    const int*   ei     = (const int*)d_in[3];   // int32 per harness contract
    const float* W1 = (const float*)d_in[4];
    const float* b1 = (const float*)d_in[5];
    const float* W2 = (const float*)d_in[6];
    const float* b2 = (const float*)d_in[7];
    const float* W3 = (const float*)d_in[8];
    const float* b3 = (const float*)d_in[9];
    const float* W4 = (const float*)d_in[10];
    const float* b4 = (const float*)d_in[11];
    float* out = (float*)d_out;

    const long long E = in_sizes[3] / 2;
    const int nn = in_sizes[0] / EMBED;

    const size_t aggBytes = (size_t)nn * EMBED * sizeof(float);
    // agg scratch: use d_ws (fits: 25.6 MB); fall back to d_out (in-place-safe)
    float* agg = (ws_size >= aggBytes) ? (float*)d_ws : out;

    hipMemsetAsync(agg, 0, aggBytes, stream);

    const long long eblocks = (E + EPB - 1) / EPB;
    edge_kernel<<<dim3((unsigned)eblocks), dim3(256), 0, stream>>>(
        coord, rbf, ei, W1, b1, W2, b2, agg, E);
    node_kernel<<<dim3(2048), dim3(256), 0, stream>>>(
        x, agg, W3, b3, W4, b4, out, nn);
}

// Round 3
// 728.558 us; speedup vs baseline: 1.3839x; 1.3839x over previous
//
#include <hip/hip_runtime.h>

typedef __attribute__((ext_vector_type(8))) short bf16x8;
typedef __attribute__((ext_vector_type(4))) float f32x4;

constexpr int EMBED = 64;
constexpr int RBF   = 16;
constexpr int EPB   = 256;   // edges per block (4 waves x 64)
constexpr int EPW   = 64;    // edges per wave

__device__ __forceinline__ short f2bf(float f) {
    unsigned u = __float_as_uint(f);
    unsigned r = (u + 0x7fffu + ((u >> 16) & 1u)) >> 16;   // RNE
    return (short)(r & 0xffffu);
}

// ---------------------------------------------------------------------------
// Edge kernel, MFMA formulation.
// Per wave: 64 edges as 4 M-tiles of 16. Per M-tile:
//   A1[16x32] = [rbf(16) | angle | 0-pad]  (bf16)
//   h1 = SiLU(A1 @ W1p + b1)        via 4x mfma_f32_16x16x32_bf16
//   msg = h1 @ W2 + b2              via 8x mfma (K=64 -> 2 K-steps)
//   atomicAdd into agg[row]         16 coalesced 64-lane atomics
// h1 goes through a wave-private XOR-swizzled LDS tile (T2) to re-fragment.
// ---------------------------------------------------------------------------
__global__ __launch_bounds__(256, 2) void edge_kernel(
    const float* __restrict__ coord,
    const float* __restrict__ rbf,
    const int* __restrict__ edge_index,
    const float* __restrict__ W1,
    const float* __restrict__ b1,
    const float* __restrict__ W2,
    const float* __restrict__ b2,
    float* __restrict__ agg,
    long long E)
{
    __shared__ int lds_row[EPB];
    __shared__ __align__(16) short lds_s[4][16 * 64];   // per-wave 16 edges x 64 ch, swizzled

    const int tid  = threadIdx.x;
    const int lane = tid & 63;
    const int wave = tid >> 6;
    const int g = lane >> 4;     // 16-lane group 0..3
    const int c = lane & 15;
    const long long blk_e0 = (long long)blockIdx.x * EPB;

    if (tid < EPB) {
        long long e = blk_e0 + tid;
        lds_row[tid] = (e < E) ? edge_index[e] : 0;
    }
    __syncthreads();

    // ---- B fragments (held in VGPRs). B layout: n = c, k = g*8 + j ----
    bf16x8 b1f[4];
#pragma unroll
    for (int t = 0; t < 4; ++t) {
#pragma unroll
        for (int j = 0; j < 8; ++j) {
            const int k = g * 8 + j;
            const int n = t * 16 + c;
            b1f[t][j] = (k <= RBF) ? f2bf(W1[k * EMBED + n]) : (short)0;
        }
    }
    bf16x8 b2f[2][4];
#pragma unroll
    for (int kk = 0; kk < 2; ++kk)
#pragma unroll
        for (int t = 0; t < 4; ++t)
#pragma unroll
            for (int j = 0; j < 8; ++j) {
                const int k = kk * 32 + g * 8 + j;
                const int n = t * 16 + c;
                b2f[kk][t][j] = f2bf(W2[k * EMBED + n]);
            }
    float b1v[4], b2v[4];
#pragma unroll
    for (int t = 0; t < 4; ++t) {
        b1v[t] = b1[t * 16 + c];
        b2v[t] = b2[t * 16 + c];
    }

    short* const sl = lds_s[wave];
    const long long wave_e0 = blk_e0 + (long long)wave * EPW;

#pragma unroll 1
    for (int mt = 0; mt < 4; ++mt) {
        const long long e0 = wave_e0 + mt * 16;
        const int eloc0 = wave * EPW + mt * 16;
        if (e0 >= E) break;

        // ---- A1 fragment: m = c (edge), k = g*8 + j ----
        bf16x8 a1 = {};
        const long long ea = e0 + c;
        const bool ev = (ea < E);
        if (g < 2) {
            if (ev) {
                const float4 p0 = *reinterpret_cast<const float4*>(rbf + ea * RBF + g * 8);
                const float4 p1 = *reinterpret_cast<const float4*>(rbf + ea * RBF + g * 8 + 4);
                a1[0] = f2bf(p0.x); a1[1] = f2bf(p0.y); a1[2] = f2bf(p0.z); a1[3] = f2bf(p0.w);
                a1[4] = f2bf(p1.x); a1[5] = f2bf(p1.y); a1[6] = f2bf(p1.z); a1[7] = f2bf(p1.w);
            }
        } else if (g == 2) {
            if (ev) {  // k=16 element = angle, computed faithfully per reference
                const int row = lds_row[eloc0 + c];
                const int col = edge_index[E + ea];
                const float vx = coord[row * 3 + 0] - coord[col * 3 + 0];
                const float vy = coord[row * 3 + 1] - coord[col * 3 + 1];
                const float vz = coord[row * 3 + 2] - coord[col * 3 + 2];
                const float sq = vx * vx + vy * vy + vz * vz;
                const float nrm = fmaxf(sqrtf(sq), 1e-12f);
                const float inv = 1.0f / nrm;
                const float ux = vx * inv, uy = vy * inv, uz = vz * inv;
                const float s2 = ux * ux + uy * uy + uz * uz;
                // clip(-s2, -1+1e-8, 1-1e-8): both bounds round to +/-1.0f in fp32
                const float cosang = fminf(fmaxf(-s2, -1.0f), 1.0f);
                const float ang = acosf(cosang);
                a1[0] = f2bf(ang);
            }
        }

        // ---- GEMM1 + bias ----
        f32x4 acc1[4];
#pragma unroll
        for (int t = 0; t < 4; ++t) {
            f32x4 ci = {b1v[t], b1v[t], b1v[t], b1v[t]};
            acc1[t] = __builtin_amdgcn_mfma_f32_16x16x32_bf16(a1, b1f[t], ci, 0, 0, 0);
        }

        // ---- SiLU, bf16, swizzled LDS write (C layout: ch = t*16+c, edge = g*4+r) ----
#pragma unroll
        for (int t = 0; t < 4; ++t)
#pragma unroll
            for (int r = 0; r < 4; ++r) {
                const float x = acc1[t][r];
                const float s = x / (1.0f + __expf(-x));
                const int erow = g * 4 + r;
                const int byte = erow * 128 + ((t * 32 + 2 * c) ^ ((erow & 7) << 4));
                *reinterpret_cast<short*>(reinterpret_cast<char*>(sl) + byte) = f2bf(s);
            }
        __builtin_amdgcn_wave_barrier();

        // ---- A2 fragments: m = c, k = kk*32 + g*8 + j (same swizzle on read) ----
        bf16x8 a2[2];
#pragma unroll
        for (int kk = 0; kk < 2; ++kk) {
            const int byte = c * 128 + ((kk * 64 + g * 16) ^ ((c & 7) << 4));
            a2[kk] = *reinterpret_cast<const bf16x8*>(reinterpret_cast<const char*>(sl) + byte);
        }
        __builtin_amdgcn_wave_barrier();

        // ---- GEMM2 + bias ----
        f32x4 acc2[4];
#pragma unroll
        for (int t = 0; t < 4; ++t) {
            f32x4 ci = {b2v[t], b2v[t], b2v[t], b2v[t]};
            acc2[t] = __builtin_amdgcn_mfma_f32_16x16x32_bf16(a2[0], b2f[0][t], ci, 0, 0, 0);
            acc2[t] = __builtin_amdgcn_mfma_f32_16x16x32_bf16(a2[1], b2f[1][t], acc2[t], 0, 0, 0);
        }

        // ---- scatter: lane holds edge g*4+r, chan t*16+c ----
        int arow[4];
#pragma unroll
        for (int r = 0; r < 4; ++r) arow[r] = lds_row[eloc0 + g * 4 + r];
#pragma unroll
        for (int r = 0; r < 4; ++r) {
            const long long eat = e0 + g * 4 + r;
            if (eat < E) {
                float* const dst = agg + (long long)arow[r] * EMBED;
#pragma unroll
                for (int t = 0; t < 4; ++t)
                    atomicAdd(dst + t * 16 + c, acc2[t][r]);
            }
        }
    }
}

// ---------------------------------------------------------------------------
// Node kernel: out = x + W4 @ silu(W3 @ agg + b3) + b4 ; one wave per node.
// launch_bounds(256,2) so the 128-float weight arrays actually stay in VGPRs.
// ---------------------------------------------------------------------------
__global__ __launch_bounds__(256, 2) void node_kernel(
    const float* __restrict__ x,
    const float* __restrict__ agg,
    const float* __restrict__ W3,
    const float* __restrict__ b3,
    const float* __restrict__ W4,
    const float* __restrict__ b4,
    float* __restrict__ out,
    int nn)
{
    __shared__ __align__(16) float lds_s[4][EMBED];
    const int lane = threadIdx.x & 63;
    const int wave = threadIdx.x >> 6;

    float w3c[EMBED], w4c[EMBED];
#pragma unroll
    for (int j = 0; j < EMBED; ++j) w3c[j] = W3[j * EMBED + lane];
#pragma unroll
    for (int j = 0; j < EMBED; ++j) w4c[j] = W4[j * EMBED + lane];
    const float b3v = b3[lane];
    const float b4v = b4[lane];

    const float4* s4 = reinterpret_cast<const float4*>(lds_s[wave]);

    const int wid = blockIdx.x * 4 + wave;
    const int nw  = gridDim.x * 4;
    for (int n = wid; n < nn; n += nw) {
        const long long base = (long long)n * EMBED + lane;
        const float a = agg[base];

        lds_s[wave][lane] = a;
        __builtin_amdgcn_wave_barrier();

        float acc = b3v;
#pragma unroll
        for (int j4 = 0; j4 < EMBED / 4; ++j4) {
            const float4 sv = s4[j4];
            acc = fmaf(sv.x, w3c[4 * j4 + 0], acc);
            acc = fmaf(sv.y, w3c[4 * j4 + 1], acc);
            acc = fmaf(sv.z, w3c[4 * j4 + 2], acc);
            acc = fmaf(sv.w, w3c[4 * j4 + 3], acc);
        }
        const float s = acc / (1.0f + __expf(-acc));

        __builtin_amdgcn_wave_barrier();
        lds_s[wave][lane] = s;
        __builtin_amdgcn_wave_barrier();

        float acc2 = b4v;
#pragma unroll
        for (int j4 = 0; j4 < EMBED / 4; ++j4) {
            const float4 sv = s4[j4];
            acc2 = fmaf(sv.x, w4c[4 * j4 + 0], acc2);
            acc2 = fmaf(sv.y, w4c[4 * j4 + 1], acc2);
            acc2 = fmaf(sv.z, w4c[4 * j4 + 2], acc2);
            acc2 = fmaf(sv.w, w4c[4 * j4 + 3], acc2);
        }
        __builtin_amdgcn_wave_barrier();

        out[base] = x[base] + acc2;
    }
}

extern "C" void kernel_launch(void* const* d_in, const int* in_sizes, int n_in,
                              void* d_out, int out_size, void* d_ws, size_t ws_size,
                              hipStream_t stream) {
    const float* x      = (const float*)d_in[0];
    const float* coord  = (const float*)d_in[1];
    const float* rbf    = (const float*)d_in[2];
    const int*   ei     = (const int*)d_in[3];
    const float* W1 = (const float*)d_in[4];
    const float* b1 = (const float*)d_in[5];
    const float* W2 = (const float*)d_in[6];
    const float* b2 = (const float*)d_in[7];
    const float* W3 = (const float*)d_in[8];
    const float* b3 = (const float*)d_in[9];
    const float* W4 = (const float*)d_in[10];
    const float* b4 = (const float*)d_in[11];
    float* out = (float*)d_out;

    const long long E = in_sizes[3] / 2;
    const int nn = in_sizes[0] / EMBED;

    const size_t aggBytes = (size_t)nn * EMBED * sizeof(float);
    float* agg = (ws_size >= aggBytes) ? (float*)d_ws : out;

    hipMemsetAsync(agg, 0, aggBytes, stream);

    const long long eblocks = (E + EPB - 1) / EPB;
    edge_kernel<<<dim3((unsigned)eblocks), dim3(256), 0, stream>>>(
        coord, rbf, ei, W1, b1, W2, b2, agg, E);
    node_kernel<<<dim3(2048), dim3(256), 0, stream>>>(
        x, agg, W3, b3, W4, b4, out, nn);
}